// Round 14
// baseline (131.879 us; speedup 1.0000x reference)
//
#include <hip/hip_runtime.h>
#include <hip/hip_bf16.h>

#define N_ROWS 8192
#define DIM 256
#define TEMP_INV 20.0f
// logit2 = cos * 20*log2(e); with int8 quantized (x127) operands the exact
// i32 dot is converted via C2F = 20*log2(e)/127^2, then exp2.
#define C2F 1.7889516e-3f

typedef __attribute__((ext_vector_type(4))) int i32x4;

// ---------------------------------------------------------------------------
// 1) Merged prep (int8 quantization) -- unchanged from R13.
// ---------------------------------------------------------------------------
__global__ void __launch_bounds__(256) prep_kernel(
    const float* __restrict__ anc, const float* __restrict__ pos,
    const float* __restrict__ neg, char* __restrict__ a8,
    char* __restrict__ p8, char* __restrict__ n8,
    float* __restrict__ diag, float* __restrict__ rowsum,
    float* __restrict__ out) {
  __shared__ __align__(16) char t8[8192];   // one k-major i8 panel
  const int lane = threadIdx.x & 63;
  const int w = threadIdx.x >> 6;

  if (blockIdx.x < 2048) {                   // ---- anchor rows ----
    int wid = blockIdx.x * 4 + w;            // row 0..8191
    float4 a = reinterpret_cast<const float4*>(anc + (size_t)wid * DIM)[lane];
    float4 p = reinterpret_cast<const float4*>(pos + (size_t)wid * DIM)[lane];
    float d  = a.x * p.x + a.y * p.y + a.z * p.z + a.w * p.w;
    float na = a.x * a.x + a.y * a.y + a.z * a.z + a.w * a.w;
    float np = p.x * p.x + p.y * p.y + p.z * p.z + p.w * p.w;
#pragma unroll
    for (int m = 32; m; m >>= 1) {
      d  += __shfl_xor(d, m);
      na += __shfl_xor(na, m);
      np += __shfl_xor(np, m);
    }
    float rna = fmaxf(sqrtf(na), 1e-8f);
    float s = 127.0f / rna;
    int q0 = (int)rintf(a.x * s), q1 = (int)rintf(a.y * s);
    int q2 = (int)rintf(a.z * s), q3 = (int)rintf(a.w * s);
    unsigned pk = (q0 & 0xFF) | ((q1 & 0xFF) << 8) |
                  ((q2 & 0xFF) << 16) | ((q3 & 0xFF) << 24);
    *reinterpret_cast<unsigned*>(a8 + (size_t)wid * DIM + (lane << 2)) = pk;
    if (lane == 0) {
      diag[wid] = TEMP_INV * d / (rna * fmaxf(sqrtf(np), 1e-8f));
      rowsum[wid] = 0.f;
    }
    return;
  }
  // ---- P/N k-major i8 panels ----
  const int b = blockIdx.x - 2048;           // 0..511
  if (b == 511 && threadIdx.x == 0) out[0] = 0.f;
  const float* src = (b < 256) ? pos : neg;
  char* dst = (b < 256) ? p8 : n8;
  const int pb = b & 255;
#pragma unroll
  for (int i = 0; i < 8; ++i) {
    int r = i * 4 + w;                       // row (col of B) within panel
    float4 v = reinterpret_cast<const float4*>(src + (size_t)(pb * 32 + r) * DIM)[lane];
    float ss = v.x * v.x + v.y * v.y + v.z * v.z + v.w * v.w;
#pragma unroll
    for (int m = 32; m; m >>= 1) ss += __shfl_xor(ss, m);
    float s = 127.0f / fmaxf(sqrtf(ss), 1e-8f);
    int q0 = (int)rintf(v.x * s), q1 = (int)rintf(v.y * s);
    int q2 = (int)rintf(v.z * s), q3 = (int)rintf(v.w * s);
    unsigned pk = (q0 & 0xFF) | ((q1 & 0xFF) << 8) |
                  ((q2 & 0xFF) << 16) | ((q3 & 0xFF) << 24);
    // lane holds k = 4*lane..4*lane+3 -> k0 = lane>>2, off = 4*(lane&3)
    *reinterpret_cast<unsigned*>(t8 + ((lane >> 2) << 9) + (r << 4) +
                                 ((lane & 3) << 2)) = pk;
  }
  __syncthreads();
  const uint4* ts = reinterpret_cast<const uint4*>(t8);
  uint4* outp = reinterpret_cast<uint4*>(dst + (size_t)pb * 8192);
  outp[threadIdx.x]       = ts[threadIdx.x];
  outp[threadIdx.x + 256] = ts[threadIdx.x + 256];
}

// ---------------------------------------------------------------------------
// 2) Fused GEMM + row-sum(exp2) -- i8 MFMA with per-wave pipe co-filling.
//    R13 counters: MfmaUtil 26.5 + VALUBusy 41 = 68% combined -- pipes are
//    co-dominant but serialized within each wave (epilogue after MFMA chain).
//    This round (mechanism: MFMA and VALU are separate pipes; one wave can
//    co-fill both if instructions are textually interleaved):
//    (a) acc ping-pong accA/accB: previous cluster's 16-elem exp2 epilogue
//        is interleaved 4-at-a-time between the current cluster's 4-MFMA
//        quads.
//    (b) bf ping-pong bfP/bfQ: next cluster's 4 ds_read_b128 issued 2 quads
//        ahead of use -> lgkm stall only on the cross-barrier cluster.
//    (c) 2 panels per barrier: 8 barriers total (was 16); ring-4 slots,
//        counted vmcnt(4) steady / 0 tail (panels 2j,2j+1 guaranteed, 2j+2,
//        2j+3 in flight). STAGE(2j+4,2j+5) overwrites slots consumed at
//        iteration j-1 (reads retired before this barrier).
//    First-cluster dummy epilogue on zeroed accB (exp2(0)=1) compensated by
//    -1.0 at the reduction. k-major panels -> all ds_reads linear-in-lane,
//    0 conflicts (R4-R13). i32 dot exact; epilogue exp2f(acc * C2F).
//    MFMA C layout (shape-determined, verified): col=lane&15, row=(lane>>4)*4+q.
// ---------------------------------------------------------------------------
__global__ void __launch_bounds__(256, 3) fused_kernel(
    const char* __restrict__ a8, const char* __restrict__ p8,
    const char* __restrict__ n8, float* __restrict__ rowsum) {
  __shared__ __align__(16) char smem[4 * 8192];   // ring of 4 x 8KB panels
  const int tid  = threadIdx.x;
  const int lane = tid & 63;
  const int w    = tid >> 6;          // 0..3
  const int rb   = blockIdx.x >> 5;   // 0..31 (256 rows each)
  const int cc   = blockIdx.x & 31;   // 0..31 (512 cols = 16 panels each)
  const char* B = (cc < 16) ? (p8 + (size_t)cc * 16 * 8192)
                            : (n8 + (size_t)(cc - 16) * 16 * 8192);
  const int row0 = rb * 256 + w * 64;
  const int ar = lane & 15;           // fragment row/col index
  const int g  = lane >> 4;           // k-group within fragment
  const int vbase = (g << 9) + (ar << 4);  // lane byte-offset within a panel

  // A fragments: 64 rows x K=256 i8 = 4rf x 4km x i32x4 (64 regs, pinned).
  i32x4 af[4][4];
#pragma unroll
  for (int rf = 0; rf < 4; ++rf)
#pragma unroll
    for (int km = 0; km < 4; ++km) {
      af[rf][km] = *reinterpret_cast<const i32x4*>(
          a8 + (size_t)(row0 + rf * 16 + ar) * DIM + km * 64 + g * 16);
      asm volatile("" : "+v"(af[rf][km]));   // non-remat def: stays resident
    }

#define STAGE(p)                                                               \
  {                                                                            \
    _Pragma("unroll")                                                          \
    for (int j = 0; j < 2; ++j) {                                              \
      const int L = (w << 1) | j;                                              \
      const char* src = B + ((size_t)(p) << 13) + (L << 10) + (lane << 4);     \
      char* dst = (char*)smem + (((p) & 3) << 13) + (L << 10);                 \
      __builtin_amdgcn_global_load_lds(                                        \
          (const __attribute__((address_space(1))) void*)src,                  \
          (__attribute__((address_space(3))) void*)dst, 16, 0, 0);             \
    }                                                                          \
  }

#define LDV(p) (*reinterpret_cast<const i32x4*>(p))
#define MMI(A, Bf, C) __builtin_amdgcn_mfma_i32_16x16x64_i8((A), (Bf), (C), 0, 0, 0)
#define EPI(ACCP, e) \
  psum[(e) >> 2][(e) & 3] += __builtin_amdgcn_exp2f((float)ACCP[(e) >> 2][(e) & 3] * C2F)

  // One cluster (16 cols, K=256): 16 MFMA in 4 quads; previous cluster's
  // 16-elem epilogue interleaved 4/quad; next cluster's 4 ds_read_b128
  // issued after quads 2 and 3 (DO_PRE).
#define CLUSTER(ACCC, ACCP, BFC, BFN, NADDR, DO_PRE)                           \
  {                                                                            \
    ACCC[0] = MMI(af[0][0], BFC[0], zeroi);                                    \
    ACCC[1] = MMI(af[1][0], BFC[0], zeroi);                                    \
    ACCC[2] = MMI(af[2][0], BFC[0], zeroi);                                    \
    ACCC[3] = MMI(af[3][0], BFC[0], zeroi);                                    \
    EPI(ACCP, 0); EPI(ACCP, 1); EPI(ACCP, 2); EPI(ACCP, 3);                    \
    ACCC[0] = MMI(af[0][1], BFC[1], ACCC[0]);                                  \
    ACCC[1] = MMI(af[1][1], BFC[1], ACCC[1]);                                  \
    ACCC[2] = MMI(af[2][1], BFC[1], ACCC[2]);                                  \
    ACCC[3] = MMI(af[3][1], BFC[1], ACCC[3]);                                  \
    EPI(ACCP, 4); EPI(ACCP, 5); EPI(ACCP, 6); EPI(ACCP, 7);                    \
    ACCC[0] = MMI(af[0][2], BFC[2], ACCC[0]);                                  \
    ACCC[1] = MMI(af[1][2], BFC[2], ACCC[1]);                                  \
    ACCC[2] = MMI(af[2][2], BFC[2], ACCC[2]);                                  \
    ACCC[3] = MMI(af[3][2], BFC[2], ACCC[3]);                                  \
    EPI(ACCP, 8); EPI(ACCP, 9); EPI(ACCP, 10); EPI(ACCP, 11);                  \
    if (DO_PRE) { BFN[0] = LDV(NADDR); BFN[1] = LDV((NADDR) + 2048); }         \
    ACCC[0] = MMI(af[0][3], BFC[3], ACCC[0]);                                  \
    ACCC[1] = MMI(af[1][3], BFC[3], ACCC[1]);                                  \
    ACCC[2] = MMI(af[2][3], BFC[3], ACCC[2]);                                  \
    ACCC[3] = MMI(af[3][3], BFC[3], ACCC[3]);                                  \
    EPI(ACCP, 12); EPI(ACCP, 13); EPI(ACCP, 14); EPI(ACCP, 15);                \
    if (DO_PRE) { BFN[2] = LDV((NADDR) + 4096); BFN[3] = LDV((NADDR) + 6144); }\
  }

  float psum[4][4];
#pragma unroll
  for (int rf = 0; rf < 4; ++rf)
#pragma unroll
    for (int q = 0; q < 4; ++q) psum[rf][q] = 0.f;
  const i32x4 zeroi = {0, 0, 0, 0};

  i32x4 bfP[4], bfQ[4];
  i32x4 accA[4], accB[4];
  accB[0] = zeroi; accB[1] = zeroi; accB[2] = zeroi; accB[3] = zeroi;  // dummy

  STAGE(0); STAGE(1); STAGE(2); STAGE(3);   // 8 loads/wave outstanding
  for (int j = 0; j < 8; ++j) {             // 2 panels per iteration
    // panels 2j,2j+1 guaranteed; 2j+2,2j+3 stay in flight (counted).
    if (j <= 6) asm volatile("s_waitcnt vmcnt(4)" ::: "memory");
    else        asm volatile("s_waitcnt vmcnt(0)" ::: "memory");
    __builtin_amdgcn_s_barrier();
    const char* pb0 = smem + (((2 * j) & 3) << 13) + vbase;
    const char* pb1 = smem + (((2 * j + 1) & 3) << 13) + vbase;
    // First cluster's B-quad (not prefetchable across the barrier).
#pragma unroll
    for (int km = 0; km < 4; ++km)
      bfP[km] = LDV(pb0 + (km << 11));
    if (j <= 5) { STAGE(2 * j + 4); STAGE(2 * j + 5); }
    CLUSTER(accA, accB, bfP, bfQ, pb0 + 256, true);   // (p0,cf0), pre (p0,cf1)
    CLUSTER(accB, accA, bfQ, bfP, pb1, true);         // (p0,cf1), pre (p1,cf0)
    CLUSTER(accA, accB, bfP, bfQ, pb1 + 256, true);   // (p1,cf0), pre (p1,cf1)
    CLUSTER(accB, accA, bfQ, bfP, pb1, false);        // (p1,cf1), no pre
  }
  // Final epilogue for the very last cluster.
#pragma unroll
  for (int e = 0; e < 16; ++e) { EPI(accB, e); }

  // Reduce over the 16 column-lanes (vary ar, keep g); -1.0 compensates the
  // first-cluster dummy epilogue (exp2(0)=1 added once per element).
#pragma unroll
  for (int rf = 0; rf < 4; ++rf)
#pragma unroll
    for (int q = 0; q < 4; ++q) {
      float s = psum[rf][q] - 1.0f;
      s += __shfl_xor(s, 1);
      s += __shfl_xor(s, 2);
      s += __shfl_xor(s, 4);
      s += __shfl_xor(s, 8);
      if (ar == 0)
        atomicAdd(rowsum + row0 + rf * 16 + g * 4 + q, s);
    }
#undef STAGE
#undef CLUSTER
#undef EPI
#undef MMI
#undef LDV
}

// ---------------------------------------------------------------------------
// 3) loss: grid 16 x 512 thr, one row per thread;
//    out[0] (+)= block-partials / N   (out zero-initialized in prep).
// ---------------------------------------------------------------------------
__global__ void __launch_bounds__(512) loss_kernel(
    const float* __restrict__ rowsum, const float* __restrict__ diag,
    float* __restrict__ out) {
  __shared__ float sh[8];
  int i = blockIdx.x * 512 + threadIdx.x;    // exactly covers 8192 rows
  float acc = logf(rowsum[i]) - diag[i];
#pragma unroll
  for (int m = 32; m; m >>= 1) acc += __shfl_xor(acc, m);
  if ((threadIdx.x & 63) == 0) sh[threadIdx.x >> 6] = acc;
  __syncthreads();
  if (threadIdx.x == 0) {
    float t = 0.f;
#pragma unroll
    for (int j = 0; j < 8; ++j) t += sh[j];
    atomicAdd(out, t / (float)N_ROWS);
  }
}

// ---------------------------------------------------------------------------
extern "C" void kernel_launch(void* const* d_in, const int* in_sizes, int n_in,
                              void* d_out, int out_size, void* d_ws, size_t ws_size,
                              hipStream_t stream) {
  const float* anc = (const float*)d_in[0];
  const float* pos = (const float*)d_in[1];
  const float* neg = (const float*)d_in[2];
  char* ws = (char*)d_ws;
  char* a8 = ws;                                  // [8192][256] i8 row-major
  char* p8 = ws + (size_t)N_ROWS * DIM;           // k-major i8 panels (2MB)
  char* n8 = p8 + (size_t)N_ROWS * DIM;
  float* diag = (float*)(ws + (size_t)3 * N_ROWS * DIM);  // 8192 f32
  float* rowsum = diag + N_ROWS;                          // 8192 f32
  float* out = (float*)d_out;

  prep_kernel<<<2048 + 512, 256, 0, stream>>>(anc, pos, neg, a8, p8, n8, diag, rowsum, out);
  fused_kernel<<<32 * 32, 256, 0, stream>>>(a8, p8, n8, rowsum);
  loss_kernel<<<16, 512, 0, stream>>>(rowsum, diag, out);
}

// Round 15
// 60.317 us; speedup vs baseline: 2.1864x; 2.1864x over previous
//
#include <hip/hip_runtime.h>
#include <hip/hip_bf16.h>

#define N_ROWS 8192
#define DIM 256
#define TEMP_INV 20.0f
// logit2 = cos * 20*log2(e); with int8 quantized (x127) operands the exact
// i32 dot is converted via C2F = 20*log2(e)/127^2, then exp2.
#define C2F 1.7889516e-3f

typedef __attribute__((ext_vector_type(4))) int i32x4;

// ---------------------------------------------------------------------------
// 1) Merged prep (int8 quantization) -- unchanged from R13 (proven).
// ---------------------------------------------------------------------------
__global__ void __launch_bounds__(256) prep_kernel(
    const float* __restrict__ anc, const float* __restrict__ pos,
    const float* __restrict__ neg, char* __restrict__ a8,
    char* __restrict__ p8, char* __restrict__ n8,
    float* __restrict__ diag, float* __restrict__ rowsum,
    float* __restrict__ out) {
  __shared__ __align__(16) char t8[8192];   // one k-major i8 panel
  const int lane = threadIdx.x & 63;
  const int w = threadIdx.x >> 6;

  if (blockIdx.x < 2048) {                   // ---- anchor rows ----
    int wid = blockIdx.x * 4 + w;            // row 0..8191
    float4 a = reinterpret_cast<const float4*>(anc + (size_t)wid * DIM)[lane];
    float4 p = reinterpret_cast<const float4*>(pos + (size_t)wid * DIM)[lane];
    float d  = a.x * p.x + a.y * p.y + a.z * p.z + a.w * p.w;
    float na = a.x * a.x + a.y * a.y + a.z * a.z + a.w * a.w;
    float np = p.x * p.x + p.y * p.y + p.z * p.z + p.w * p.w;
#pragma unroll
    for (int m = 32; m; m >>= 1) {
      d  += __shfl_xor(d, m);
      na += __shfl_xor(na, m);
      np += __shfl_xor(np, m);
    }
    float rna = fmaxf(sqrtf(na), 1e-8f);
    float s = 127.0f / rna;
    int q0 = (int)rintf(a.x * s), q1 = (int)rintf(a.y * s);
    int q2 = (int)rintf(a.z * s), q3 = (int)rintf(a.w * s);
    unsigned pk = (q0 & 0xFF) | ((q1 & 0xFF) << 8) |
                  ((q2 & 0xFF) << 16) | ((q3 & 0xFF) << 24);
    *reinterpret_cast<unsigned*>(a8 + (size_t)wid * DIM + (lane << 2)) = pk;
    if (lane == 0) {
      diag[wid] = TEMP_INV * d / (rna * fmaxf(sqrtf(np), 1e-8f));
      rowsum[wid] = 0.f;
    }
    return;
  }
  // ---- P/N k-major i8 panels ----
  const int b = blockIdx.x - 2048;           // 0..511
  if (b == 511 && threadIdx.x == 0) out[0] = 0.f;
  const float* src = (b < 256) ? pos : neg;
  char* dst = (b < 256) ? p8 : n8;
  const int pb = b & 255;
#pragma unroll
  for (int i = 0; i < 8; ++i) {
    int r = i * 4 + w;                       // row (col of B) within panel
    float4 v = reinterpret_cast<const float4*>(src + (size_t)(pb * 32 + r) * DIM)[lane];
    float ss = v.x * v.x + v.y * v.y + v.z * v.z + v.w * v.w;
#pragma unroll
    for (int m = 32; m; m >>= 1) ss += __shfl_xor(ss, m);
    float s = 127.0f / fmaxf(sqrtf(ss), 1e-8f);
    int q0 = (int)rintf(v.x * s), q1 = (int)rintf(v.y * s);
    int q2 = (int)rintf(v.z * s), q3 = (int)rintf(v.w * s);
    unsigned pk = (q0 & 0xFF) | ((q1 & 0xFF) << 8) |
                  ((q2 & 0xFF) << 16) | ((q3 & 0xFF) << 24);
    // lane holds k = 4*lane..4*lane+3 -> k0 = lane>>2, off = 4*(lane&3)
    *reinterpret_cast<unsigned*>(t8 + ((lane >> 2) << 9) + (r << 4) +
                                 ((lane & 3) << 2)) = pk;
  }
  __syncthreads();
  const uint4* ts = reinterpret_cast<const uint4*>(t8);
  uint4* outp = reinterpret_cast<uint4*>(dst + (size_t)pb * 8192);
  outp[threadIdx.x]       = ts[threadIdx.x];
  outp[threadIdx.x + 256] = ts[threadIdx.x + 256];
}

// ---------------------------------------------------------------------------
// 2) Fused GEMM + row-sum(exp2) -- i8 MFMA, R13 structure, 4 waves/SIMD.
//    R14 post-mortem: cross-cluster ping-pong state spilled at (256,3) cap.
//    Reverted. This round's single lever: OCCUPANCY. i8 halved per-wave reg
//    needs; halve the wave tile too (32 rows/wave: af = 2rf x 4km = 32 regs;
//    total ~85 << 128-reg cap) -> __launch_bounds__(256,4) = 4 waves/SIMD,
//    4 resident blocks/CU (LDS 4 x 32KB = 128KB). Strongest cross-round
//    signal: combined pipe util tracks waves/SIMD (2w->61%, 3w->68%).
//    Pipe check per panel: MFMA 1305 cy/SIMD > LDS-read 1024 cy/CU > VALU
//    ~800 cy/SIMD -> MFMA-dominant; floor 17.4us.
//    Grid: 64 rb (BM=128) x 32 cc = 2048 blocks (= 8/CU, 2 clean rounds).
//    Everything else byte-identical to R13: ring-4 8KB k-major panels,
//    STAGE = 2 global_load_lds/wave/panel, counted vmcnt(4)/2/0, ONE
//    barrier/panel, ds_reads linear-in-lane (0 conflicts R4-R14), exact
//    i32 dot, epilogue exp2f(acc * C2F).
//    MFMA C layout (shape-determined, verified): col=lane&15, row=(lane>>4)*4+q.
// ---------------------------------------------------------------------------
__global__ void __launch_bounds__(256, 4) fused_kernel(
    const char* __restrict__ a8, const char* __restrict__ p8,
    const char* __restrict__ n8, float* __restrict__ rowsum) {
  __shared__ __align__(16) char smem[4 * 8192];   // ring of 4 x 8KB panels
  const int tid  = threadIdx.x;
  const int lane = tid & 63;
  const int w    = tid >> 6;          // 0..3
  const int rb   = blockIdx.x >> 5;   // 0..63 (128 rows each)
  const int cc   = blockIdx.x & 31;   // 0..31 (512 cols = 16 panels each)
  const char* B = (cc < 16) ? (p8 + (size_t)cc * 16 * 8192)
                            : (n8 + (size_t)(cc - 16) * 16 * 8192);
  const int row0 = rb * 128 + w * 32;
  const int ar = lane & 15;           // fragment row/col index
  const int g  = lane >> 4;           // k-group within fragment
  const int vbase = (g << 9) + (ar << 4);  // lane byte-offset within a panel

  // A fragments: 32 rows x K=256 i8 = 2rf x 4km x i32x4 (32 regs, pinned).
  i32x4 af[2][4];
#pragma unroll
  for (int rf = 0; rf < 2; ++rf)
#pragma unroll
    for (int km = 0; km < 4; ++km) {
      af[rf][km] = *reinterpret_cast<const i32x4*>(
          a8 + (size_t)(row0 + rf * 16 + ar) * DIM + km * 64 + g * 16);
      asm volatile("" : "+v"(af[rf][km]));   // non-remat def: stays resident
    }

  // Stage panel `p` (8KB contiguous) into ring slot p&3: 2 loads/wave.
#define STAGE(p)                                                               \
  {                                                                            \
    _Pragma("unroll")                                                          \
    for (int j = 0; j < 2; ++j) {                                              \
      const int L = (w << 1) | j;                                              \
      const char* src = B + ((size_t)(p) << 13) + (L << 10) + (lane << 4);     \
      char* dst = (char*)smem + (((p) & 3) << 13) + (L << 10);                 \
      __builtin_amdgcn_global_load_lds(                                        \
          (const __attribute__((address_space(1))) void*)src,                  \
          (__attribute__((address_space(3))) void*)dst, 16, 0, 0);             \
    }                                                                          \
  }

#define MMI(A, Bf, C) __builtin_amdgcn_mfma_i32_16x16x64_i8((A), (Bf), (C), 0, 0, 0)

  // One cf-cluster: 4 ds_read_b128 + 8 MFMA + 8-elem exp2 epilogue.
#define CLUSTER(CFOFF)                                                         \
  {                                                                            \
    i32x4 bf[4];                                                               \
    _Pragma("unroll")                                                          \
    for (int km = 0; km < 4; ++km)                                             \
      bf[km] = *reinterpret_cast<const i32x4*>(pbase + (km << 11) + (CFOFF));  \
    i32x4 acc[2];                                                              \
    _Pragma("unroll")                                                          \
    for (int rf = 0; rf < 2; ++rf) acc[rf] = MMI(af[rf][0], bf[0], zeroi);     \
    _Pragma("unroll")                                                          \
    for (int km = 1; km < 4; ++km)                                             \
      _Pragma("unroll")                                                        \
      for (int rf = 0; rf < 2; ++rf)                                           \
        acc[rf] = MMI(af[rf][km], bf[km], acc[rf]);                            \
    _Pragma("unroll")                                                          \
    for (int rf = 0; rf < 2; ++rf)                                             \
      _Pragma("unroll")                                                        \
      for (int q = 0; q < 4; ++q)                                              \
        psum[rf][q] += __builtin_amdgcn_exp2f((float)acc[rf][q] * C2F);        \
  }

  float psum[2][4];
#pragma unroll
  for (int rf = 0; rf < 2; ++rf)
#pragma unroll
    for (int q = 0; q < 4; ++q) psum[rf][q] = 0.f;
  const i32x4 zeroi = {0, 0, 0, 0};

  STAGE(0);
  STAGE(1);
  STAGE(2);   // 6 loads/wave outstanding
  for (int it = 0; it < 16; ++it) {
    // Counted waits: own panel-`it` loads done; newer panels stay in flight.
    if (it <= 13)      asm volatile("s_waitcnt vmcnt(4)" ::: "memory");
    else if (it == 14) asm volatile("s_waitcnt vmcnt(2)" ::: "memory");
    else               asm volatile("s_waitcnt vmcnt(0)" ::: "memory");
    __builtin_amdgcn_s_barrier();
    const char* pbase = smem + ((it & 3) << 13) + vbase;
    CLUSTER(0);                      // cf0 (cols ar)
    if (it <= 12) STAGE(it + 3);     // overwrites slot (it-1)&3: reads retired
    CLUSTER(256);                    // cf1 (cols 16+ar)
  }

  // Reduce over the 16 column-lanes (vary ar, keep g); accumulate per row.
#pragma unroll
  for (int rf = 0; rf < 2; ++rf)
#pragma unroll
    for (int q = 0; q < 4; ++q) {
      float s = psum[rf][q];
      s += __shfl_xor(s, 1);
      s += __shfl_xor(s, 2);
      s += __shfl_xor(s, 4);
      s += __shfl_xor(s, 8);
      if (ar == 0)
        atomicAdd(rowsum + row0 + rf * 16 + g * 4 + q, s);
    }
#undef STAGE
#undef CLUSTER
#undef MMI
}

// ---------------------------------------------------------------------------
// 3) loss: grid 16 x 512 thr, one row per thread;
//    out[0] (+)= block-partials / N   (out zero-initialized in prep).
// ---------------------------------------------------------------------------
__global__ void __launch_bounds__(512) loss_kernel(
    const float* __restrict__ rowsum, const float* __restrict__ diag,
    float* __restrict__ out) {
  __shared__ float sh[8];
  int i = blockIdx.x * 512 + threadIdx.x;    // exactly covers 8192 rows
  float acc = logf(rowsum[i]) - diag[i];
#pragma unroll
  for (int m = 32; m; m >>= 1) acc += __shfl_xor(acc, m);
  if ((threadIdx.x & 63) == 0) sh[threadIdx.x >> 6] = acc;
  __syncthreads();
  if (threadIdx.x == 0) {
    float t = 0.f;
#pragma unroll
    for (int j = 0; j < 8; ++j) t += sh[j];
    atomicAdd(out, t / (float)N_ROWS);
  }
}

// ---------------------------------------------------------------------------
extern "C" void kernel_launch(void* const* d_in, const int* in_sizes, int n_in,
                              void* d_out, int out_size, void* d_ws, size_t ws_size,
                              hipStream_t stream) {
  const float* anc = (const float*)d_in[0];
  const float* pos = (const float*)d_in[1];
  const float* neg = (const float*)d_in[2];
  char* ws = (char*)d_ws;
  char* a8 = ws;                                  // [8192][256] i8 row-major
  char* p8 = ws + (size_t)N_ROWS * DIM;           // k-major i8 panels (2MB)
  char* n8 = p8 + (size_t)N_ROWS * DIM;
  float* diag = (float*)(ws + (size_t)3 * N_ROWS * DIM);  // 8192 f32
  float* rowsum = diag + N_ROWS;                          // 8192 f32
  float* out = (float*)d_out;

  prep_kernel<<<2048 + 512, 256, 0, stream>>>(anc, pos, neg, a8, p8, n8, diag, rowsum, out);
  fused_kernel<<<64 * 32, 256, 0, stream>>>(a8, p8, n8, rowsum);
  loss_kernel<<<16, 512, 0, stream>>>(rowsum, diag, out);
}

// Round 16
// 56.894 us; speedup vs baseline: 2.3180x; 1.0602x over previous
//
#include <hip/hip_runtime.h>
#include <hip/hip_bf16.h>

#define N_ROWS 8192
#define DIM 256
#define TEMP_INV 20.0f
// logit2 = cos * 20*log2(e); with int8 quantized (x127) operands the exact
// i32 dot is converted via C2F = 20*log2(e)/127^2, then exp2.
#define C2F 1.7889516e-3f

typedef __attribute__((ext_vector_type(4))) int i32x4;

// ---------------------------------------------------------------------------
// 1) Merged prep (int8 quantization) -- unchanged from R13 (proven).
// ---------------------------------------------------------------------------
__global__ void __launch_bounds__(256) prep_kernel(
    const float* __restrict__ anc, const float* __restrict__ pos,
    const float* __restrict__ neg, char* __restrict__ a8,
    char* __restrict__ p8, char* __restrict__ n8,
    float* __restrict__ diag, float* __restrict__ rowsum,
    float* __restrict__ out) {
  __shared__ __align__(16) char t8[8192];   // one k-major i8 panel
  const int lane = threadIdx.x & 63;
  const int w = threadIdx.x >> 6;

  if (blockIdx.x < 2048) {                   // ---- anchor rows ----
    int wid = blockIdx.x * 4 + w;            // row 0..8191
    float4 a = reinterpret_cast<const float4*>(anc + (size_t)wid * DIM)[lane];
    float4 p = reinterpret_cast<const float4*>(pos + (size_t)wid * DIM)[lane];
    float d  = a.x * p.x + a.y * p.y + a.z * p.z + a.w * p.w;
    float na = a.x * a.x + a.y * a.y + a.z * a.z + a.w * a.w;
    float np = p.x * p.x + p.y * p.y + p.z * p.z + p.w * p.w;
#pragma unroll
    for (int m = 32; m; m >>= 1) {
      d  += __shfl_xor(d, m);
      na += __shfl_xor(na, m);
      np += __shfl_xor(np, m);
    }
    float rna = fmaxf(sqrtf(na), 1e-8f);
    float s = 127.0f / rna;
    int q0 = (int)rintf(a.x * s), q1 = (int)rintf(a.y * s);
    int q2 = (int)rintf(a.z * s), q3 = (int)rintf(a.w * s);
    unsigned pk = (q0 & 0xFF) | ((q1 & 0xFF) << 8) |
                  ((q2 & 0xFF) << 16) | ((q3 & 0xFF) << 24);
    *reinterpret_cast<unsigned*>(a8 + (size_t)wid * DIM + (lane << 2)) = pk;
    if (lane == 0) {
      diag[wid] = TEMP_INV * d / (rna * fmaxf(sqrtf(np), 1e-8f));
      rowsum[wid] = 0.f;
    }
    return;
  }
  // ---- P/N k-major i8 panels ----
  const int b = blockIdx.x - 2048;           // 0..511
  if (b == 511 && threadIdx.x == 0) out[0] = 0.f;
  const float* src = (b < 256) ? pos : neg;
  char* dst = (b < 256) ? p8 : n8;
  const int pb = b & 255;
#pragma unroll
  for (int i = 0; i < 8; ++i) {
    int r = i * 4 + w;                       // row (col of B) within panel
    float4 v = reinterpret_cast<const float4*>(src + (size_t)(pb * 32 + r) * DIM)[lane];
    float ss = v.x * v.x + v.y * v.y + v.z * v.z + v.w * v.w;
#pragma unroll
    for (int m = 32; m; m >>= 1) ss += __shfl_xor(ss, m);
    float s = 127.0f / fmaxf(sqrtf(ss), 1e-8f);
    int q0 = (int)rintf(v.x * s), q1 = (int)rintf(v.y * s);
    int q2 = (int)rintf(v.z * s), q3 = (int)rintf(v.w * s);
    unsigned pk = (q0 & 0xFF) | ((q1 & 0xFF) << 8) |
                  ((q2 & 0xFF) << 16) | ((q3 & 0xFF) << 24);
    // lane holds k = 4*lane..4*lane+3 -> k0 = lane>>2, off = 4*(lane&3)
    *reinterpret_cast<unsigned*>(t8 + ((lane >> 2) << 9) + (r << 4) +
                                 ((lane & 3) << 2)) = pk;
  }
  __syncthreads();
  const uint4* ts = reinterpret_cast<const uint4*>(t8);
  uint4* outp = reinterpret_cast<uint4*>(dst + (size_t)pb * 8192);
  outp[threadIdx.x]       = ts[threadIdx.x];
  outp[threadIdx.x + 256] = ts[threadIdx.x + 256];
}

// ---------------------------------------------------------------------------
// 2) Fused GEMM + row-sum(exp2) -- i8 MFMA, R15 structure, ring-3 LDS probe.
//    R15 anomaly: occupancy pinned at ~33% (~2.5-3 blocks/CU) at 32KB LDS
//    despite VGPR=44 and (256,4) -- LDS residency is the prime suspect
//    (m132: 64KB -> ~2 blocks; 32KB -> ~3). Single lever this round: shrink
//    the ring to 3 x 8KB = 24KB/block. If LDS was the binder, residency and
//    combined pipe util (the one correlation proven across 15 rounds) rise
//    proportionally.
//    Ring-3 discipline: prologue STAGE(0,1); per iter: wait vmcnt(2) (tail
//    it=15: 0) -> own panel-`it` loads done, panel it+1 in flight; barrier;
//    STAGE(it+2) into slot (it+2)%3 == slot of panel it-1, whose readers all
//    passed barrier(it) -> WAR-safe. Never drains vmcnt in steady state.
//    Everything else identical to R15: BM=128 (32 rows/wave, af = 2rf x 4km,
//    32 regs pinned), 8KB k-major panels, ds_reads linear-in-lane (0
//    conflicts R4-R15), exact i32 dot, epilogue exp2f(acc * C2F).
//    MFMA C layout (shape-determined, verified): col=lane&15, row=(lane>>4)*4+q.
// ---------------------------------------------------------------------------
__global__ void __launch_bounds__(256, 4) fused_kernel(
    const char* __restrict__ a8, const char* __restrict__ p8,
    const char* __restrict__ n8, float* __restrict__ rowsum) {
  __shared__ __align__(16) char smem[3 * 8192];   // ring of 3 x 8KB panels
  const int tid  = threadIdx.x;
  const int lane = tid & 63;
  const int w    = tid >> 6;          // 0..3
  const int rb   = blockIdx.x >> 5;   // 0..63 (128 rows each)
  const int cc   = blockIdx.x & 31;   // 0..31 (512 cols = 16 panels each)
  const char* B = (cc < 16) ? (p8 + (size_t)cc * 16 * 8192)
                            : (n8 + (size_t)(cc - 16) * 16 * 8192);
  const int row0 = rb * 128 + w * 32;
  const int ar = lane & 15;           // fragment row/col index
  const int g  = lane >> 4;           // k-group within fragment
  const int vbase = (g << 9) + (ar << 4);  // lane byte-offset within a panel

  // A fragments: 32 rows x K=256 i8 = 2rf x 4km x i32x4 (32 regs, pinned).
  i32x4 af[2][4];
#pragma unroll
  for (int rf = 0; rf < 2; ++rf)
#pragma unroll
    for (int km = 0; km < 4; ++km) {
      af[rf][km] = *reinterpret_cast<const i32x4*>(
          a8 + (size_t)(row0 + rf * 16 + ar) * DIM + km * 64 + g * 16);
      asm volatile("" : "+v"(af[rf][km]));   // non-remat def: stays resident
    }

  // Stage panel `p` (8KB contiguous) into ring slot `slot`: 2 loads/wave.
#define STAGE(slot, p)                                                         \
  {                                                                            \
    _Pragma("unroll")                                                          \
    for (int j = 0; j < 2; ++j) {                                              \
      const int L = (w << 1) | j;                                              \
      const char* src = B + ((size_t)(p) << 13) + (L << 10) + (lane << 4);     \
      char* dst = (char*)smem + ((slot) << 13) + (L << 10);                    \
      __builtin_amdgcn_global_load_lds(                                        \
          (const __attribute__((address_space(1))) void*)src,                  \
          (__attribute__((address_space(3))) void*)dst, 16, 0, 0);             \
    }                                                                          \
  }

#define MMI(A, Bf, C) __builtin_amdgcn_mfma_i32_16x16x64_i8((A), (Bf), (C), 0, 0, 0)

  // One cf-cluster: 4 ds_read_b128 + 8 MFMA + 8-elem exp2 epilogue.
#define CLUSTER(CFOFF)                                                         \
  {                                                                            \
    i32x4 bf[4];                                                               \
    _Pragma("unroll")                                                          \
    for (int km = 0; km < 4; ++km)                                             \
      bf[km] = *reinterpret_cast<const i32x4*>(pbase + (km << 11) + (CFOFF));  \
    i32x4 acc[2];                                                              \
    _Pragma("unroll")                                                          \
    for (int rf = 0; rf < 2; ++rf) acc[rf] = MMI(af[rf][0], bf[0], zeroi);     \
    _Pragma("unroll")                                                          \
    for (int km = 1; km < 4; ++km)                                             \
      _Pragma("unroll")                                                        \
      for (int rf = 0; rf < 2; ++rf)                                           \
        acc[rf] = MMI(af[rf][km], bf[km], acc[rf]);                            \
    _Pragma("unroll")                                                          \
    for (int rf = 0; rf < 2; ++rf)                                             \
      _Pragma("unroll")                                                        \
      for (int q = 0; q < 4; ++q)                                              \
        psum[rf][q] += __builtin_amdgcn_exp2f((float)acc[rf][q] * C2F);        \
  }

  float psum[2][4];
#pragma unroll
  for (int rf = 0; rf < 2; ++rf)
#pragma unroll
    for (int q = 0; q < 4; ++q) psum[rf][q] = 0.f;
  const i32x4 zeroi = {0, 0, 0, 0};

  STAGE(0, 0);
  STAGE(1, 1);          // 4 loads/wave outstanding
  int rd = 0;           // slot of panel `it` (= it % 3)
  for (int it = 0; it < 16; ++it) {
    // Own panel-`it` loads done; panel it+1 stays in flight (counted).
    if (it <= 14) asm volatile("s_waitcnt vmcnt(2)" ::: "memory");
    else          asm volatile("s_waitcnt vmcnt(0)" ::: "memory");
    __builtin_amdgcn_s_barrier();
    const char* pbase = smem + (rd << 13) + vbase;
    const int st = (rd == 0) ? 2 : rd - 1;   // (it+2)%3 == (it-1)%3
    CLUSTER(0);                        // cf0 (cols ar)
    if (it <= 13) STAGE(st, it + 2);   // slot of panel it-1: readers retired
    CLUSTER(256);                      // cf1 (cols 16+ar)
    rd = (rd == 2) ? 0 : rd + 1;
  }

  // Reduce over the 16 column-lanes (vary ar, keep g); accumulate per row.
#pragma unroll
  for (int rf = 0; rf < 2; ++rf)
#pragma unroll
    for (int q = 0; q < 4; ++q) {
      float s = psum[rf][q];
      s += __shfl_xor(s, 1);
      s += __shfl_xor(s, 2);
      s += __shfl_xor(s, 4);
      s += __shfl_xor(s, 8);
      if (ar == 0)
        atomicAdd(rowsum + row0 + rf * 16 + g * 4 + q, s);
    }
#undef STAGE
#undef CLUSTER
#undef MMI
}

// ---------------------------------------------------------------------------
// 3) loss: grid 16 x 512 thr, one row per thread;
//    out[0] (+)= block-partials / N   (out zero-initialized in prep).
// ---------------------------------------------------------------------------
__global__ void __launch_bounds__(512) loss_kernel(
    const float* __restrict__ rowsum, const float* __restrict__ diag,
    float* __restrict__ out) {
  __shared__ float sh[8];
  int i = blockIdx.x * 512 + threadIdx.x;    // exactly covers 8192 rows
  float acc = logf(rowsum[i]) - diag[i];
#pragma unroll
  for (int m = 32; m; m >>= 1) acc += __shfl_xor(acc, m);
  if ((threadIdx.x & 63) == 0) sh[threadIdx.x >> 6] = acc;
  __syncthreads();
  if (threadIdx.x == 0) {
    float t = 0.f;
#pragma unroll
    for (int j = 0; j < 8; ++j) t += sh[j];
    atomicAdd(out, t / (float)N_ROWS);
  }
}

// ---------------------------------------------------------------------------
extern "C" void kernel_launch(void* const* d_in, const int* in_sizes, int n_in,
                              void* d_out, int out_size, void* d_ws, size_t ws_size,
                              hipStream_t stream) {
  const float* anc = (const float*)d_in[0];
  const float* pos = (const float*)d_in[1];
  const float* neg = (const float*)d_in[2];
  char* ws = (char*)d_ws;
  char* a8 = ws;                                  // [8192][256] i8 row-major
  char* p8 = ws + (size_t)N_ROWS * DIM;           // k-major i8 panels (2MB)
  char* n8 = p8 + (size_t)N_ROWS * DIM;
  float* diag = (float*)(ws + (size_t)3 * N_ROWS * DIM);  // 8192 f32
  float* rowsum = diag + N_ROWS;                          // 8192 f32
  float* out = (float*)d_out;

  prep_kernel<<<2048 + 512, 256, 0, stream>>>(anc, pos, neg, a8, p8, n8, diag, rowsum, out);
  fused_kernel<<<64 * 32, 256, 0, stream>>>(a8, p8, n8, rowsum);
  loss_kernel<<<16, 512, 0, stream>>>(rowsum, diag, out);
}